// Round 4
// baseline (453.742 us; speedup 1.0000x reference)
//
#include <hip/hip_runtime.h>

// ---------------------------------------------------------------------------
// GATEncoder fused pipeline, fp32 baseline (R3: fixed signed-overflow in
// packed CSR ebuf — (e<<14)|src overflowed int for e >= 2^17, corrupting
// alpha for ~39k edges incl. all self-loops; ebuf is now unsigned).
// enc1 GEMM -> LN+ReLU -> enc2 GEMM -> gat GEMM -> attn coefs ->
// edge weights (+counts) -> scan -> scatter(CSR, packed) -> gather-agg ->
// skip GEMM (+conv+bias, ELU) -> dec1 GEMM (leaky) -> dec2 GEMV.
// edge_index dtype (int32 vs int64) is detected at runtime on device.
// ---------------------------------------------------------------------------

#define N_NODES  10000
#define N_EDGES  160000
#define E_TOT    (N_EDGES + N_NODES)   // with self-loops
#define NBATCH   8192
#define DIM_IN   128
#define DIM_H    256
#define DIM_GAT  512                    // HEADS*HOUT
#define DIM_DEC  1024

// ---------------------------------------------------------------------------
// Templated register-tiled GEMM:  C[M,N] = act( A[M,K] @ W[N,K]^T + bias +
//                                               bias2 + addmat )
// ACT: 0 none, 1 leaky(0.1), 2 elu(0.1).  In-place C==addmat is safe
// (same thread reads then writes the same element).
// ---------------------------------------------------------------------------
template<int BM, int BN, int BK, int TM, int TN, int ACT>
__global__ __launch_bounds__(256)
void gemm_kernel(const float* __restrict__ A, const float* __restrict__ W,
                 const float* __restrict__ bias, const float* __restrict__ bias2,
                 const float* __restrict__ addmat,
                 float* __restrict__ C, int M, int N, int K)
{
    constexpr int TX = BN / TN;      // threads along N
    constexpr int TY = BM / TM;      // threads along M
    static_assert(TX * TY == 256, "block must be 256 threads");
    __shared__ float As[BK][BM + 4];
    __shared__ float Ws[BK][BN + 4];

    const int tid = threadIdx.x;
    const int tx  = tid % TX;
    const int ty  = tid / TX;
    const int bm  = blockIdx.x * BM;
    const int bn  = blockIdx.y * BN;

    float acc[TM][TN];
    #pragma unroll
    for (int i = 0; i < TM; ++i)
        #pragma unroll
        for (int j = 0; j < TN; ++j) acc[i][j] = 0.f;

    constexpr int A_LOADS = BM * BK / 4 / 256;   // float4 loads per thread
    constexpr int W_LOADS = BN * BK / 4 / 256;
    constexpr int KQ = BK / 4;

    for (int k0 = 0; k0 < K; k0 += BK) {
        #pragma unroll
        for (int l = 0; l < A_LOADS; ++l) {
            int idx  = tid + l * 256;
            int row  = idx / KQ;
            int kq   = idx % KQ;
            int grow = bm + row;
            float4 v = make_float4(0.f, 0.f, 0.f, 0.f);
            if (grow < M)
                v = *reinterpret_cast<const float4*>(&A[(size_t)grow * K + k0 + kq * 4]);
            As[kq * 4 + 0][row] = v.x;
            As[kq * 4 + 1][row] = v.y;
            As[kq * 4 + 2][row] = v.z;
            As[kq * 4 + 3][row] = v.w;
        }
        #pragma unroll
        for (int l = 0; l < W_LOADS; ++l) {
            int idx  = tid + l * 256;
            int row  = idx / KQ;
            int kq   = idx % KQ;
            int grow = bn + row;      // N is always a multiple of BN here
            float4 v = *reinterpret_cast<const float4*>(&W[(size_t)grow * K + k0 + kq * 4]);
            Ws[kq * 4 + 0][row] = v.x;
            Ws[kq * 4 + 1][row] = v.y;
            Ws[kq * 4 + 2][row] = v.z;
            Ws[kq * 4 + 3][row] = v.w;
        }
        __syncthreads();
        #pragma unroll
        for (int kk = 0; kk < BK; ++kk) {
            float af[TM], wf[TN];
            #pragma unroll
            for (int i = 0; i < TM; ++i) af[i] = As[kk][ty * TM + i];
            #pragma unroll
            for (int j = 0; j < TN; ++j) wf[j] = Ws[kk][tx * TN + j];
            #pragma unroll
            for (int i = 0; i < TM; ++i)
                #pragma unroll
                for (int j = 0; j < TN; ++j)
                    acc[i][j] = fmaf(af[i], wf[j], acc[i][j]);
        }
        __syncthreads();
    }

    #pragma unroll
    for (int i = 0; i < TM; ++i) {
        int grow = bm + ty * TM + i;
        if (grow < M) {
            #pragma unroll
            for (int j = 0; j < TN; ++j) {
                int gcol = bn + tx * TN + j;
                float v = acc[i][j];
                if (bias)   v += bias[gcol];
                if (bias2)  v += bias2[gcol];
                if (addmat) v += addmat[(size_t)grow * N + gcol];
                if (ACT == 1) v = v > 0.f ? v : 0.1f * v;
                else if (ACT == 2) v = v > 0.f ? v : 0.1f * (expf(v) - 1.f);
                C[(size_t)grow * N + gcol] = v;
            }
        }
    }
}

// ---------------------------------------------------------------------------
// edge_index dtype detection: if the input is int64 (little-endian, all
// indices < 2^31), every odd int32 word of the first 64 pairs is 0.
// stride 2 => int64, stride 1 => int32. Written to eflag[0] each call.
// ---------------------------------------------------------------------------
__global__ void detect_kernel(const int* __restrict__ ei32, int* __restrict__ eflag)
{
    if (blockIdx.x == 0 && threadIdx.x == 0) {
        int s = 0;
        #pragma unroll
        for (int i = 0; i < 64; ++i) s |= ei32[2 * i + 1];
        eflag[0] = (s == 0) ? 2 : 1;
    }
}

// ---------------------------------------------------------------------------
// LayerNorm(256) + ReLU, in place. One wave per row (4 rows / block).
// ---------------------------------------------------------------------------
__global__ __launch_bounds__(256)
void ln_relu_kernel(float* __restrict__ h, const float* __restrict__ g,
                    const float* __restrict__ b)
{
    int wave = threadIdx.x >> 6, lane = threadIdx.x & 63;
    int row = blockIdx.x * 4 + wave;
    if (row >= N_NODES) return;
    float4 v = *reinterpret_cast<const float4*>(&h[(size_t)row * DIM_H + lane * 4]);
    float s  = v.x + v.y + v.z + v.w;
    float sq = v.x * v.x + v.y * v.y + v.z * v.z + v.w * v.w;
    #pragma unroll
    for (int m = 1; m <= 32; m <<= 1) { s += __shfl_xor(s, m); sq += __shfl_xor(sq, m); }
    float mu  = s * (1.0f / 256.0f);
    float var = sq * (1.0f / 256.0f) - mu * mu;
    float rs  = 1.0f / sqrtf(var + 1e-5f);
    float4 gg = *reinterpret_cast<const float4*>(&g[lane * 4]);
    float4 bb = *reinterpret_cast<const float4*>(&b[lane * 4]);
    float4 o;
    o.x = fmaxf((v.x - mu) * rs * gg.x + bb.x, 0.f);
    o.y = fmaxf((v.y - mu) * rs * gg.y + bb.y, 0.f);
    o.z = fmaxf((v.z - mu) * rs * gg.z + bb.z, 0.f);
    o.w = fmaxf((v.w - mu) * rs * gg.w + bb.w, 0.f);
    *reinterpret_cast<float4*>(&h[(size_t)row * DIM_H + lane * 4]) = o;
}

// ---------------------------------------------------------------------------
// Per-node attention coefficients: a_src/a_dst [N,2].
// att vectors are [2,256] flat = 512 floats matching the xs row layout.
// One wave per node; lanes 0..31 -> head 0, lanes 32..63 -> head 1.
// ---------------------------------------------------------------------------
__global__ __launch_bounds__(256)
void attn_coef_kernel(const float* __restrict__ xs,
                      const float* __restrict__ att_src,
                      const float* __restrict__ att_dst,
                      float* __restrict__ asrc, float* __restrict__ adst)
{
    int wave = threadIdx.x >> 6, lane = threadIdx.x & 63;
    int node = blockIdx.x * 4 + wave;
    if (node >= N_NODES) return;
    const float4* xr = reinterpret_cast<const float4*>(&xs[(size_t)node * DIM_GAT + lane * 8]);
    const float4* sr = reinterpret_cast<const float4*>(&att_src[lane * 8]);
    const float4* dr = reinterpret_cast<const float4*>(&att_dst[lane * 8]);
    float ss = 0.f, sd = 0.f;
    #pragma unroll
    for (int q = 0; q < 2; ++q) {
        float4 a = xr[q], s = sr[q], d = dr[q];
        ss += a.x * s.x + a.y * s.y + a.z * s.z + a.w * s.w;
        sd += a.x * d.x + a.y * d.y + a.z * d.z + a.w * d.w;
    }
    #pragma unroll
    for (int m = 1; m <= 16; m <<= 1) { ss += __shfl_xor(ss, m); sd += __shfl_xor(sd, m); }
    if ((lane & 31) == 0) {
        int hh = lane >> 5;
        asrc[node * 2 + hh] = ss;
        adst[node * 2 + hh] = sd;
    }
}

// ---------------------------------------------------------------------------
// Edge pass: w = exp(leaky(a_src[src]+a_dst[tgt], 0.2)); z[tgt] += w;
// counts[tgt] += 1. Max-subtraction skipped: alpha = w/z is identical and
// |e| is bounded ~2 at this weight scale, so exp cannot overflow.
// ---------------------------------------------------------------------------
__global__ __launch_bounds__(256)
void edge_w_kernel(const int* __restrict__ ei, const int* __restrict__ eflag,
                   const float* __restrict__ asrc, const float* __restrict__ adst,
                   float* __restrict__ wbuf, float* __restrict__ zbuf,
                   int* __restrict__ counts)
{
    int e = blockIdx.x * 256 + threadIdx.x;
    if (e >= E_TOT) return;
    const int stride = eflag[0];
    int src, tgt;
    if (e < N_EDGES) {
        src = ei[(size_t)stride * e];
        tgt = ei[(size_t)stride * (N_EDGES + e)];
    } else {
        src = tgt = e - N_EDGES;
    }
    #pragma unroll
    for (int hh = 0; hh < 2; ++hh) {
        float v = asrc[src * 2 + hh] + adst[tgt * 2 + hh];
        v = v > 0.f ? v : 0.2f * v;
        float w = expf(v);
        wbuf[e * 2 + hh] = w;
        atomicAdd(&zbuf[tgt * 2 + hh], w);
    }
    atomicAdd(&counts[tgt], 1);
}

// ---------------------------------------------------------------------------
// Exclusive prefix sum over counts[N_NODES] -> rowst[N_NODES+1].
// One block, 10 elements per thread, single Hillis-Steele over partials.
// ---------------------------------------------------------------------------
__global__ __launch_bounds__(1024)
void scan_kernel(const int* __restrict__ counts, int* __restrict__ rowst)
{
    __shared__ int part[1024];
    const int t = threadIdx.x;
    const int base = t * 10;
    int loc[10];
    int s = 0;
    #pragma unroll
    for (int i = 0; i < 10; ++i) {
        int idx = base + i;
        int v = (idx < N_NODES) ? counts[idx] : 0;
        loc[i] = s;                 // exclusive within chunk
        s += v;
    }
    part[t] = s;
    __syncthreads();
    for (int off = 1; off < 1024; off <<= 1) {
        int v = (t >= off) ? part[t - off] : 0;
        __syncthreads();
        part[t] += v;
        __syncthreads();
    }
    int chunk_excl = part[t] - s;   // exclusive prefix of this chunk
    #pragma unroll
    for (int i = 0; i < 10; ++i) {
        int idx = base + i;
        if (idx <= N_NODES) rowst[idx] = chunk_excl + loc[i];
    }
}

// ---------------------------------------------------------------------------
// Scatter packed (edge_id << 14 | src) into CSR buckets by target.
// e < 2^18 (170000), src < 2^14 (10000). e<<14 exceeds 2^31 for e >= 2^17,
// so the packed word MUST be unsigned (R3 fix: was int -> sign-extended
// arithmetic unpack shift corrupted ~39k edges incl. all self-loops).
// ---------------------------------------------------------------------------
__global__ __launch_bounds__(256)
void scatter_kernel(const int* __restrict__ ei, const int* __restrict__ eflag,
                    const int* __restrict__ rowst,
                    int* __restrict__ cursor, unsigned int* __restrict__ ebuf)
{
    int e = blockIdx.x * 256 + threadIdx.x;
    if (e >= E_TOT) return;
    const int stride = eflag[0];
    int src, tgt;
    if (e < N_EDGES) {
        src = ei[(size_t)stride * e];
        tgt = ei[(size_t)stride * (N_EDGES + e)];
    } else {
        src = tgt = e - N_EDGES;
    }
    int pos = atomicAdd(&cursor[tgt], 1);
    ebuf[rowst[tgt] + pos] = ((unsigned int)e << 14) | (unsigned int)src;
}

// ---------------------------------------------------------------------------
// Gather-aggregate: agg[n, :] = sum_e alpha_e * xs[src_e, :], n < NBATCH.
// One block (256 threads) per target; thread t owns cols t (head0) and
// 256+t (head1). Logical (unsigned) shift on unpack.
// ---------------------------------------------------------------------------
__global__ __launch_bounds__(256)
void agg_kernel(const float* __restrict__ xs,
                const float* __restrict__ wbuf, const float* __restrict__ zbuf,
                const int* __restrict__ rowst, const unsigned int* __restrict__ ebuf,
                float* __restrict__ agg)
{
    int n = blockIdx.x;           // target node (< NBATCH)
    int t = threadIdx.x;
    float inv0 = 1.0f / zbuf[n * 2 + 0];
    float inv1 = 1.0f / zbuf[n * 2 + 1];
    float acc0 = 0.f, acc1 = 0.f;
    int beg = rowst[n], end = rowst[n + 1];
    for (int j = beg; j < end; ++j) {
        unsigned int pk = ebuf[j];
        int e   = (int)(pk >> 14);          // logical shift: e in [0, 170000)
        int src = (int)(pk & 0x3FFFu);
        float a0 = wbuf[e * 2 + 0] * inv0;
        float a1 = wbuf[e * 2 + 1] * inv1;
        const float* xr = &xs[(size_t)src * DIM_GAT];
        acc0 = fmaf(xr[t], a0, acc0);
        acc1 = fmaf(xr[256 + t], a1, acc1);
    }
    agg[(size_t)n * DIM_GAT + t]       = acc0;
    agg[(size_t)n * DIM_GAT + 256 + t] = acc1;
}

// ---------------------------------------------------------------------------
// dec2 GEMV: y[m] = dot(d[m,:1024], w2) + b2. One wave per row.
// ---------------------------------------------------------------------------
__global__ __launch_bounds__(256)
void gemv_kernel(const float* __restrict__ d, const float* __restrict__ w2,
                 const float* __restrict__ b2, float* __restrict__ y)
{
    int wave = threadIdx.x >> 6, lane = threadIdx.x & 63;
    int row = blockIdx.x * 4 + wave;
    if (row >= NBATCH) return;
    const float4* dr = reinterpret_cast<const float4*>(&d[(size_t)row * DIM_DEC + lane * 16]);
    const float4* wr = reinterpret_cast<const float4*>(&w2[lane * 16]);
    float s = 0.f;
    #pragma unroll
    for (int q = 0; q < 4; ++q) {
        float4 a = dr[q], b = wr[q];
        s += a.x * b.x + a.y * b.y + a.z * b.z + a.w * b.w;
    }
    #pragma unroll
    for (int m = 1; m <= 32; m <<= 1) s += __shfl_xor(s, m);
    if (lane == 0) y[row] = s + b2[0];
}

// ---------------------------------------------------------------------------
extern "C" void kernel_launch(void* const* d_in, const int* in_sizes, int n_in,
                              void* d_out, int out_size, void* d_ws, size_t ws_size,
                              hipStream_t stream)
{
    const float* x        = (const float*)d_in[0];
    const int*   ei       = (const int*)  d_in[1];
    const float* enc_w1   = (const float*)d_in[3];
    const float* enc_b1   = (const float*)d_in[4];
    const float* ln_g     = (const float*)d_in[5];
    const float* ln_b     = (const float*)d_in[6];
    const float* enc_w2   = (const float*)d_in[7];
    const float* enc_b2   = (const float*)d_in[8];
    const float* gat_w    = (const float*)d_in[9];
    const float* att_src  = (const float*)d_in[10];
    const float* att_dst  = (const float*)d_in[11];
    const float* gat_bias = (const float*)d_in[12];
    const float* skip_w   = (const float*)d_in[13];
    const float* skip_b   = (const float*)d_in[14];
    const float* dec_w1   = (const float*)d_in[15];
    const float* dec_b1   = (const float*)d_in[16];
    const float* dec_w2   = (const float*)d_in[17];
    const float* dec_b2   = (const float*)d_in[18];
    float* y = (float*)d_out;

    // -------- workspace layout (floats), overlays are phase-disjoint -------
    float* ws = (float*)d_ws;
    float* R1   = ws;                         // 8,388,608 floats
    float* h1   = R1;                         // [10000,256] (encoder phase)
    float* h    = R1 + 2560000;               // [10000,256]
    float* dbuf = R1;                         // [8192,1024] (decoder phase)
    float* R2   = R1 + 8388608;               // 5,120,000 floats
    float* xs   = R2;                         // [10000,512] (gat phase)
    float* outb = R2;                         // [8192,512]  (after agg)
    float* agg  = R2 + 5120000;               // [8192,512]
    float* S    = agg + 4194304;
    float* asrc   = S;                        // [10000,2]
    float* adst   = S + 20000;                // [10000,2]
    float* wbuf   = S + 40000;                // [170000,2]
    float* zbuf   = S + 380000;               // [10000,2]
    int*   counts = (int*)(S + 400000);       // [10000]
    int*   cursor = counts + 10000;           // [10000]
    int*   rowst  = cursor + 10000;           // [10001]
    unsigned int* ebuf = (unsigned int*)(rowst + 10001); // [170000] (e<<14)|src
    int*   eflag  = (int*)(ebuf + 170000);    // [1]

    // zero z / counts / cursor (contiguous 40000 * 4 bytes)
    hipMemsetAsync(zbuf, 0, 40000 * sizeof(float), stream);
    // detect edge_index dtype (int32 vs int64) -> eflag
    detect_kernel<<<1, 1, 0, stream>>>(ei, eflag);

    // ------------------------------ pipeline -------------------------------
    // enc1: h1 = x @ enc_w1^T + b1
    gemm_kernel<64, 64, 16, 4, 4, 0><<<dim3(157, 4), 256, 0, stream>>>(
        x, enc_w1, enc_b1, nullptr, nullptr, h1, N_NODES, DIM_H, DIM_IN);
    // LN + ReLU in place
    ln_relu_kernel<<<2500, 256, 0, stream>>>(h1, ln_g, ln_b);
    // enc2: h = h1 @ enc_w2^T + b2
    gemm_kernel<64, 64, 16, 4, 4, 0><<<dim3(157, 4), 256, 0, stream>>>(
        h1, enc_w2, enc_b2, nullptr, nullptr, h, N_NODES, DIM_H, DIM_H);
    // gat lin: xs = h @ gat_w^T
    gemm_kernel<64, 64, 16, 4, 4, 0><<<dim3(157, 8), 256, 0, stream>>>(
        h, gat_w, nullptr, nullptr, nullptr, xs, N_NODES, DIM_GAT, DIM_H);
    // attention coefficients
    attn_coef_kernel<<<2500, 256, 0, stream>>>(xs, att_src, att_dst, asrc, adst);
    // edge weights + z + degree counts
    edge_w_kernel<<<(E_TOT + 255) / 256, 256, 0, stream>>>(
        ei, eflag, asrc, adst, wbuf, zbuf, counts);
    // CSR
    scan_kernel<<<1, 1024, 0, stream>>>(counts, rowst);
    scatter_kernel<<<(E_TOT + 255) / 256, 256, 0, stream>>>(
        ei, eflag, rowst, cursor, ebuf);
    // aggregate (only batch targets needed downstream)
    agg_kernel<<<NBATCH, 256, 0, stream>>>(xs, wbuf, zbuf, rowst, ebuf, agg);
    // skip GEMM + conv + biases + ELU(0.1):
    // outb = elu(agg + gat_bias + h[:8192] @ skip_w^T + skip_b)
    gemm_kernel<64, 64, 16, 4, 4, 2><<<dim3(128, 8), 256, 0, stream>>>(
        h, skip_w, skip_b, gat_bias, agg, outb, NBATCH, DIM_GAT, DIM_H);
    // dec1 + leaky(0.1)
    gemm_kernel<128, 128, 16, 8, 8, 1><<<dim3(64, 8), 256, 0, stream>>>(
        outb, dec_w1, dec_b1, nullptr, nullptr, dbuf, NBATCH, DIM_DEC, DIM_GAT);
    // dec2 GEMV -> y
    gemv_kernel<<<NBATCH / 4, 256, 0, stream>>>(dbuf, dec_w2, dec_b2, y);
}

// Round 10
// 296.717 us; speedup vs baseline: 1.5292x; 1.5292x over previous
//
#include <hip/hip_runtime.h>

// ---------------------------------------------------------------------------
// GATEncoder fused pipeline. R9 = audited R8 resubmit (broker timeouts):
//  - big GEMMs (enc2/gat/skip/dec1) via split-bf16 3-pass MFMA
//    (A=Ah+Al, W=Wh+Wl; C = AhWh + AhWl + AlWh, ~1e-5 accuracy)
//  - dec2 GEMV fused into dec1 epilogue (atomicAdd into y)
//  - dec_b2 added once (wc==0 guard); MFMA frag type = short8.
// enc1 stays fp32. Edge/attn/CSR path unchanged from R3 (validated).
// ---------------------------------------------------------------------------

#define N_NODES  10000
#define N_EDGES  160000
#define E_TOT    (N_EDGES + N_NODES)
#define NBATCH   8192
#define DIM_IN   128
#define DIM_H    256
#define DIM_GAT  512
#define DIM_DEC  1024
#define MPAD     10112                 // 79 * 128

typedef short bf16x8 __attribute__((ext_vector_type(8)));   // 8 bf16 in 4 VGPRs
typedef float f32x4  __attribute__((ext_vector_type(4)));

__device__ __forceinline__ ushort f2bf(float f) {
    union { float f; unsigned u; } c; c.f = f;
    unsigned u = c.u + 0x7FFFu + ((c.u >> 16) & 1u);   // RNE
    return (ushort)(u >> 16);
}
__device__ __forceinline__ float bf2f(ushort h) {
    union { unsigned u; float f; } c; c.u = ((unsigned)h) << 16; return c.f;
}

// ---------------------------------------------------------------------------
// fp32 register-tiled GEMM (enc1 only: [10000,128] @ [128->256]).
// ---------------------------------------------------------------------------
template<int BM, int BN, int BK, int TM, int TN>
__global__ __launch_bounds__(256)
void gemm_kernel(const float* __restrict__ A, const float* __restrict__ W,
                 const float* __restrict__ bias, float* __restrict__ C,
                 int M, int N, int K)
{
    constexpr int TX = BN / TN;
    constexpr int TY = BM / TM;
    static_assert(TX * TY == 256, "block must be 256 threads");
    __shared__ float As[BK][BM + 4];
    __shared__ float Ws[BK][BN + 4];

    const int tid = threadIdx.x;
    const int tx  = tid % TX;
    const int ty  = tid / TX;
    const int bm  = blockIdx.x * BM;
    const int bn  = blockIdx.y * BN;

    float acc[TM][TN];
    #pragma unroll
    for (int i = 0; i < TM; ++i)
        #pragma unroll
        for (int j = 0; j < TN; ++j) acc[i][j] = 0.f;

    constexpr int A_LOADS = BM * BK / 4 / 256;
    constexpr int W_LOADS = BN * BK / 4 / 256;
    constexpr int KQ = BK / 4;

    for (int k0 = 0; k0 < K; k0 += BK) {
        #pragma unroll
        for (int l = 0; l < A_LOADS; ++l) {
            int idx = tid + l * 256, row = idx / KQ, kq = idx % KQ;
            int grow = bm + row;
            float4 v = make_float4(0.f, 0.f, 0.f, 0.f);
            if (grow < M)
                v = *reinterpret_cast<const float4*>(&A[(size_t)grow * K + k0 + kq * 4]);
            As[kq * 4 + 0][row] = v.x; As[kq * 4 + 1][row] = v.y;
            As[kq * 4 + 2][row] = v.z; As[kq * 4 + 3][row] = v.w;
        }
        #pragma unroll
        for (int l = 0; l < W_LOADS; ++l) {
            int idx = tid + l * 256, row = idx / KQ, kq = idx % KQ;
            float4 v = *reinterpret_cast<const float4*>(&W[(size_t)(bn + row) * K + k0 + kq * 4]);
            Ws[kq * 4 + 0][row] = v.x; Ws[kq * 4 + 1][row] = v.y;
            Ws[kq * 4 + 2][row] = v.z; Ws[kq * 4 + 3][row] = v.w;
        }
        __syncthreads();
        #pragma unroll
        for (int kk = 0; kk < BK; ++kk) {
            float af[TM], wf[TN];
            #pragma unroll
            for (int i = 0; i < TM; ++i) af[i] = As[kk][ty * TM + i];
            #pragma unroll
            for (int j = 0; j < TN; ++j) wf[j] = Ws[kk][tx * TN + j];
            #pragma unroll
            for (int i = 0; i < TM; ++i)
                #pragma unroll
                for (int j = 0; j < TN; ++j)
                    acc[i][j] = fmaf(af[i], wf[j], acc[i][j]);
        }
        __syncthreads();
    }

    #pragma unroll
    for (int i = 0; i < TM; ++i) {
        int grow = bm + ty * TM + i;
        if (grow < M) {
            #pragma unroll
            for (int j = 0; j < TN; ++j) {
                int gcol = bn + tx * TN + j;
                C[(size_t)grow * N + gcol] = acc[i][j] + bias[gcol];
            }
        }
    }
}

// ---------------------------------------------------------------------------
// Split-bf16 MFMA GEMM: C[M,N] = A[M,K] @ W[N,K]^T, 3-pass hi/lo.
// 128x128x64 tile, 4 waves (2x2), each wave 64x64 (4x4 16x16x32 frags).
// LDS tiles [128 rows][64 bf16] with 16B-chunk XOR swizzle
// byte ^= ((row&7)<<4): inverse-swizzled global SOURCE + linear
// global_load_lds dest + swizzled ds_read (both-sides rule).
// EPI: 0 = fp32 out (gat);    1 = +bias, split hi/lo out (enc2);
//      2 = +bias+bias2+addmat, ELU(0.1), split hi/lo out (skip);
//      3 = +bias, leaky(0.1), fused dot-with-w2 -> atomicAdd y (dec1+dec2).
// ---------------------------------------------------------------------------
__device__ __forceinline__ void stage_tile(ushort* T, const ushort* __restrict__ G,
                                           int rowbase, int K, int k0, int tid, int wv)
{
    #pragma unroll
    for (int i = 0; i < 4; ++i) {
        int m   = i * 32 + (tid >> 3);                       // tile row
        int scb = ((tid & 7) << 4) ^ ((m & 7) << 4);         // src col byte (inv swz)
        const char* gsrc = (const char*)G + ((size_t)(rowbase + m) * K + k0) * 2 + scb;
        char* ldst = (char*)T + i * 4096 + wv * 1024;        // wave-uniform base
        __builtin_amdgcn_global_load_lds(
            (const __attribute__((address_space(1))) void*)gsrc,
            (__attribute__((address_space(3))) void*)ldst, 16, 0, 0);
    }
}

__device__ __forceinline__ bf16x8 ldfrag(const ushort* T, int row, int kcb)
{
    int addr = (row << 7) + (kcb ^ ((row & 7) << 4));        // swizzled read
    return *reinterpret_cast<const bf16x8*>(reinterpret_cast<const char*>(T) + addr);
}

template<int EPI>
__global__ __launch_bounds__(256, 2)
void mgemm(const ushort* __restrict__ Ah, const ushort* __restrict__ Al,
           const ushort* __restrict__ Wh, const ushort* __restrict__ Wl,
           const float* __restrict__ bias, const float* __restrict__ bias2,
           const float* __restrict__ addmat, float* __restrict__ outF,
           ushort* __restrict__ outHi, ushort* __restrict__ outLo,
           const float* __restrict__ w2, const float* __restrict__ b2,
           float* __restrict__ yout, int M, int N, int K)
{
    __shared__ __align__(16) ushort tAh[8192];
    __shared__ __align__(16) ushort tAl[8192];
    __shared__ __align__(16) ushort tWh[8192];
    __shared__ __align__(16) ushort tWl[8192];

    const int tid    = threadIdx.x;
    const int lane   = tid & 63;
    const int wv     = tid >> 6;
    const int wr     = wv >> 1, wc = wv & 1;
    const int bm     = blockIdx.x * 128;
    const int bn     = blockIdx.y * 128;
    const int lane15 = lane & 15;
    const int kgrp16 = (lane >> 4) << 4;      // byte offset of lane's k-slice
    const int r0     = (lane >> 4) << 2;      // C/D row group

    f32x4 acc[4][4];
    const f32x4 zero = {0.f, 0.f, 0.f, 0.f};
    #pragma unroll
    for (int i = 0; i < 4; ++i)
        #pragma unroll
        for (int j = 0; j < 4; ++j) acc[i][j] = zero;

    for (int k0 = 0; k0 < K; k0 += 64) {
        stage_tile(tAh, Ah, bm, K, k0, tid, wv);
        stage_tile(tAl, Al, bm, K, k0, tid, wv);
        stage_tile(tWh, Wh, bn, K, k0, tid, wv);
        stage_tile(tWl, Wl, bn, K, k0, tid, wv);
        __syncthreads();                       // drains vmcnt before barrier
        #pragma unroll
        for (int kk = 0; kk < 2; ++kk) {
            const int kcb = kk * 64 + kgrp16;
            bf16x8 ah[4], al[4], wh[4], wl[4];
            #pragma unroll
            for (int f = 0; f < 4; ++f) {
                ah[f] = ldfrag(tAh, wr * 64 + f * 16 + lane15, kcb);
                al[f] = ldfrag(tAl, wr * 64 + f * 16 + lane15, kcb);
                wh[f] = ldfrag(tWh, wc * 64 + f * 16 + lane15, kcb);
                wl[f] = ldfrag(tWl, wc * 64 + f * 16 + lane15, kcb);
            }
            #pragma unroll
            for (int fm = 0; fm < 4; ++fm)
                #pragma unroll
                for (int fn = 0; fn < 4; ++fn) {
                    acc[fm][fn] = __builtin_amdgcn_mfma_f32_16x16x32_bf16(ah[fm], wh[fn], acc[fm][fn], 0, 0, 0);
                    acc[fm][fn] = __builtin_amdgcn_mfma_f32_16x16x32_bf16(ah[fm], wl[fn], acc[fm][fn], 0, 0, 0);
                    acc[fm][fn] = __builtin_amdgcn_mfma_f32_16x16x32_bf16(al[fm], wh[fn], acc[fm][fn], 0, 0, 0);
                }
        }
        __syncthreads();
    }

    if (EPI != 3) {
        #pragma unroll
        for (int fm = 0; fm < 4; ++fm) {
            #pragma unroll
            for (int r = 0; r < 4; ++r) {
                int row = bm + wr * 64 + fm * 16 + r0 + r;
                if (row < M) {
                    #pragma unroll
                    for (int fn = 0; fn < 4; ++fn) {
                        int col = bn + wc * 64 + fn * 16 + lane15;
                        float v = acc[fm][fn][r];
                        if (EPI == 1 || EPI == 2) v += bias[col];
                        if (EPI == 2) {
                            v += bias2[col] + addmat[(size_t)row * N + col];
                            v = v > 0.f ? v : 0.1f * (expf(v) - 1.f);
                        }
                        if (EPI == 0) {
                            outF[(size_t)row * N + col] = v;
                        } else {
                            ushort h = f2bf(v);
                            outHi[(size_t)row * N + col] = h;
                            outLo[(size_t)row * N + col] = f2bf(v - bf2f(h));
                        }
                    }
                }
            }
        }
    } else {
        // dec1 + fused dec2: y[row] += sum_col leaky(acc+b1)[col] * w2[col]
        #pragma unroll
        for (int fm = 0; fm < 4; ++fm) {
            #pragma unroll
            for (int r = 0; r < 4; ++r) {
                int row = bm + wr * 64 + fm * 16 + r0 + r;
                float part = 0.f;
                #pragma unroll
                for (int fn = 0; fn < 4; ++fn) {
                    int col = bn + wc * 64 + fn * 16 + lane15;
                    float v = acc[fm][fn][r] + bias[col];
                    v = v > 0.f ? v : 0.1f * v;
                    part = fmaf(v, w2[col], part);
                }
                part += __shfl_xor(part, 1);
                part += __shfl_xor(part, 2);
                part += __shfl_xor(part, 4);
                part += __shfl_xor(part, 8);
                if (lane15 == 0 && row < M) {
                    // b2 exactly once per row: only the wc==0 wave of y-block 0
                    float add = part + ((blockIdx.y == 0 && wc == 0) ? b2[0] : 0.f);
                    atomicAdd(&yout[row], add);
                }
            }
        }
    }
}

// ---------------------------------------------------------------------------
// Weight hi/lo split (elementwise).
// ---------------------------------------------------------------------------
__global__ __launch_bounds__(256)
void split_kernel(const float* __restrict__ src, ushort* __restrict__ hi,
                  ushort* __restrict__ lo, int n)
{
    int i = blockIdx.x * 256 + threadIdx.x;
    if (i < n) {
        float v = src[i];
        ushort h = f2bf(v);
        hi[i] = h;
        lo[i] = f2bf(v - bf2f(h));
    }
}

// ---------------------------------------------------------------------------
// edge_index dtype detection (int64 vs int32), device-side.
// ---------------------------------------------------------------------------
__global__ void detect_kernel(const int* __restrict__ ei32, int* __restrict__ eflag)
{
    if (blockIdx.x == 0 && threadIdx.x == 0) {
        int s = 0;
        #pragma unroll
        for (int i = 0; i < 64; ++i) s |= ei32[2 * i + 1];
        eflag[0] = (s == 0) ? 2 : 1;
    }
}

// ---------------------------------------------------------------------------
// LayerNorm(256) + ReLU -> hi/lo bf16 pair. One wave per row.
// ---------------------------------------------------------------------------
__global__ __launch_bounds__(256)
void ln_relu_split_kernel(const float* __restrict__ h1, const float* __restrict__ g,
                          const float* __restrict__ b, ushort* __restrict__ hi,
                          ushort* __restrict__ lo)
{
    int wave = threadIdx.x >> 6, lane = threadIdx.x & 63;
    int row = blockIdx.x * 4 + wave;
    if (row >= N_NODES) return;
    float4 v = *reinterpret_cast<const float4*>(&h1[(size_t)row * DIM_H + lane * 4]);
    float s  = v.x + v.y + v.z + v.w;
    float sq = v.x * v.x + v.y * v.y + v.z * v.z + v.w * v.w;
    #pragma unroll
    for (int m = 1; m <= 32; m <<= 1) { s += __shfl_xor(s, m); sq += __shfl_xor(sq, m); }
    float mu  = s * (1.0f / 256.0f);
    float var = sq * (1.0f / 256.0f) - mu * mu;
    float rs  = 1.0f / sqrtf(var + 1e-5f);
    float4 gg = *reinterpret_cast<const float4*>(&g[lane * 4]);
    float4 bb = *reinterpret_cast<const float4*>(&b[lane * 4]);
    float o[4];
    o[0] = fmaxf((v.x - mu) * rs * gg.x + bb.x, 0.f);
    o[1] = fmaxf((v.y - mu) * rs * gg.y + bb.y, 0.f);
    o[2] = fmaxf((v.z - mu) * rs * gg.z + bb.z, 0.f);
    o[3] = fmaxf((v.w - mu) * rs * gg.w + bb.w, 0.f);
    ushort4 vh, vl;
    ushort* ph = &vh.x; ushort* pl = &vl.x;
    #pragma unroll
    for (int q = 0; q < 4; ++q) {
        ushort hh = f2bf(o[q]);
        ph[q] = hh;
        pl[q] = f2bf(o[q] - bf2f(hh));
    }
    *reinterpret_cast<ushort4*>(&hi[(size_t)row * DIM_H + lane * 4]) = vh;
    *reinterpret_cast<ushort4*>(&lo[(size_t)row * DIM_H + lane * 4]) = vl;
}

// ---------------------------------------------------------------------------
// Attention coefficients a_src/a_dst [N,2] from xs fp32.
// ---------------------------------------------------------------------------
__global__ __launch_bounds__(256)
void attn_coef_kernel(const float* __restrict__ xs,
                      const float* __restrict__ att_src,
                      const float* __restrict__ att_dst,
                      float* __restrict__ asrc, float* __restrict__ adst)
{
    int wave = threadIdx.x >> 6, lane = threadIdx.x & 63;
    int node = blockIdx.x * 4 + wave;
    if (node >= N_NODES) return;
    const float4* xr = reinterpret_cast<const float4*>(&xs[(size_t)node * DIM_GAT + lane * 8]);
    const float4* sr = reinterpret_cast<const float4*>(&att_src[lane * 8]);
    const float4* dr = reinterpret_cast<const float4*>(&att_dst[lane * 8]);
    float ss = 0.f, sd = 0.f;
    #pragma unroll
    for (int q = 0; q < 2; ++q) {
        float4 a = xr[q], s = sr[q], d = dr[q];
        ss += a.x * s.x + a.y * s.y + a.z * s.z + a.w * s.w;
        sd += a.x * d.x + a.y * d.y + a.z * d.z + a.w * d.w;
    }
    #pragma unroll
    for (int m = 1; m <= 16; m <<= 1) { ss += __shfl_xor(ss, m); sd += __shfl_xor(sd, m); }
    if ((lane & 31) == 0) {
        int hh = lane >> 5;
        asrc[node * 2 + hh] = ss;
        adst[node * 2 + hh] = sd;
    }
}

// ---------------------------------------------------------------------------
// Edge pass: w = exp(leaky(a_src[src]+a_dst[tgt],0.2)); z[tgt]+=w; counts++.
// Max-subtraction skipped: alpha = w/z is identical; |e| bounded ~2 here.
// ---------------------------------------------------------------------------
__global__ __launch_bounds__(256)
void edge_w_kernel(const int* __restrict__ ei, const int* __restrict__ eflag,
                   const float* __restrict__ asrc, const float* __restrict__ adst,
                   float* __restrict__ wbuf, float* __restrict__ zbuf,
                   int* __restrict__ counts)
{
    int e = blockIdx.x * 256 + threadIdx.x;
    if (e >= E_TOT) return;
    const int stride = eflag[0];
    int src, tgt;
    if (e < N_EDGES) {
        src = ei[(size_t)stride * e];
        tgt = ei[(size_t)stride * (N_EDGES + e)];
    } else {
        src = tgt = e - N_EDGES;
    }
    #pragma unroll
    for (int hh = 0; hh < 2; ++hh) {
        float v = asrc[src * 2 + hh] + adst[tgt * 2 + hh];
        v = v > 0.f ? v : 0.2f * v;
        float w = expf(v);
        wbuf[e * 2 + hh] = w;
        atomicAdd(&zbuf[tgt * 2 + hh], w);
    }
    atomicAdd(&counts[tgt], 1);
}

// ---------------------------------------------------------------------------
// Exclusive prefix sum counts -> rowst. One block.
// ---------------------------------------------------------------------------
__global__ __launch_bounds__(1024)
void scan_kernel(const int* __restrict__ counts, int* __restrict__ rowst)
{
    __shared__ int part[1024];
    const int t = threadIdx.x;
    const int base = t * 10;
    int loc[10];
    int s = 0;
    #pragma unroll
    for (int i = 0; i < 10; ++i) {
        int idx = base + i;
        int v = (idx < N_NODES) ? counts[idx] : 0;
        loc[i] = s;
        s += v;
    }
    part[t] = s;
    __syncthreads();
    for (int off = 1; off < 1024; off <<= 1) {
        int v = (t >= off) ? part[t - off] : 0;
        __syncthreads();
        part[t] += v;
        __syncthreads();
    }
    int chunk_excl = part[t] - s;
    #pragma unroll
    for (int i = 0; i < 10; ++i) {
        int idx = base + i;
        if (idx <= N_NODES) rowst[idx] = chunk_excl + loc[i];
    }
}

// ---------------------------------------------------------------------------
// Scatter packed (e<<14)|src (unsigned!) into CSR buckets by target.
// ---------------------------------------------------------------------------
__global__ __launch_bounds__(256)
void scatter_kernel(const int* __restrict__ ei, const int* __restrict__ eflag,
                    const int* __restrict__ rowst,
                    int* __restrict__ cursor, unsigned int* __restrict__ ebuf)
{
    int e = blockIdx.x * 256 + threadIdx.x;
    if (e >= E_TOT) return;
    const int stride = eflag[0];
    int src, tgt;
    if (e < N_EDGES) {
        src = ei[(size_t)stride * e];
        tgt = ei[(size_t)stride * (N_EDGES + e)];
    } else {
        src = tgt = e - N_EDGES;
    }
    int pos = atomicAdd(&cursor[tgt], 1);
    ebuf[rowst[tgt] + pos] = ((unsigned int)e << 14) | (unsigned int)src;
}

// ---------------------------------------------------------------------------
// Gather-aggregate: agg[n,:] = sum_e alpha_e * xs[src_e,:], n < NBATCH.
// ---------------------------------------------------------------------------
__global__ __launch_bounds__(256)
void agg_kernel(const float* __restrict__ xs,
                const float* __restrict__ wbuf, const float* __restrict__ zbuf,
                const int* __restrict__ rowst, const unsigned int* __restrict__ ebuf,
                float* __restrict__ agg)
{
    int n = blockIdx.x;
    int t = threadIdx.x;
    float inv0 = 1.0f / zbuf[n * 2 + 0];
    float inv1 = 1.0f / zbuf[n * 2 + 1];
    float acc0 = 0.f, acc1 = 0.f;
    int beg = rowst[n], end = rowst[n + 1];
    for (int j = beg; j < end; ++j) {
        unsigned int pk = ebuf[j];
        int e   = (int)(pk >> 14);
        int src = (int)(pk & 0x3FFFu);
        float a0 = wbuf[e * 2 + 0] * inv0;
        float a1 = wbuf[e * 2 + 1] * inv1;
        const float* xr = &xs[(size_t)src * DIM_GAT];
        acc0 = fmaf(xr[t], a0, acc0);
        acc1 = fmaf(xr[256 + t], a1, acc1);
    }
    agg[(size_t)n * DIM_GAT + t]       = acc0;
    agg[(size_t)n * DIM_GAT + 256 + t] = acc1;
}

// ---------------------------------------------------------------------------
extern "C" void kernel_launch(void* const* d_in, const int* in_sizes, int n_in,
                              void* d_out, int out_size, void* d_ws, size_t ws_size,
                              hipStream_t stream)
{
    const float* x        = (const float*)d_in[0];
    const int*   ei       = (const int*)  d_in[1];
    const float* enc_w1   = (const float*)d_in[3];
    const float* enc_b1   = (const float*)d_in[4];
    const float* ln_g     = (const float*)d_in[5];
    const float* ln_b     = (const float*)d_in[6];
    const float* enc_w2   = (const float*)d_in[7];
    const float* enc_b2   = (const float*)d_in[8];
    const float* gat_w    = (const float*)d_in[9];
    const float* att_src  = (const float*)d_in[10];
    const float* att_dst  = (const float*)d_in[11];
    const float* gat_bias = (const float*)d_in[12];
    const float* skip_w   = (const float*)d_in[13];
    const float* skip_b   = (const float*)d_in[14];
    const float* dec_w1   = (const float*)d_in[15];
    const float* dec_b1   = (const float*)d_in[16];
    const float* dec_w2   = (const float*)d_in[17];
    const float* dec_b2   = (const float*)d_in[18];
    float* y = (float*)d_out;

    // -------- workspace layout (floats); overlays are phase-disjoint -------
    float* ws = (float*)d_ws;
    // R0 overlay [0, 5242880):
    //   enc phase: h1 fp32 [10000*256] | h1ln_hi/lo ushort [10112*256]
    //   gat phase: xs fp32 [10000*512]   (overwrites h1/h1ln — dead by then)
    //   skip phase: outb_hi/lo ushort [8192*512] (overwrites xs — dead)
    float*  h1      = ws;
    ushort* h1ln_hi = (ushort*)(ws + 2560000);
    ushort* h1ln_lo = h1ln_hi + (size_t)MPAD * DIM_H;
    float*  xs      = ws;
    ushort* outb_hi = (ushort*)ws;
    ushort* outb_lo = outb_hi + (size_t)NBATCH * DIM_GAT;
    // B: h hi/lo (live enc2 -> skip)
    ushort* h_hi = (ushort*)(ws + 5242880);
    ushort* h_lo = h_hi + (size_t)MPAD * DIM_H;
    // D: agg fp32
    float* agg = ws + 7842880;
    // F: split weights (ushort)
    ushort* wsp = (ushort*)(ws + 12037184);
    ushort* w2h = wsp;
    ushort* w2l = w2h + 65536;
    ushort* gwh = w2l + 65536;
    ushort* gwl = gwh + 131072;
    ushort* swh = gwl + 131072;
    ushort* swl = swh + 131072;
    ushort* d1h = swl + 131072;
    ushort* d1l = d1h + 524288;
    // S: edge/attention scratch
    float* S      = ws + 12889152;
    float* asrc   = S;
    float* adst   = S + 20000;
    float* wbuf   = S + 40000;
    float* zbuf   = S + 380000;
    int*   counts = (int*)(S + 400000);
    int*   cursor = counts + 10000;
    int*   rowst  = cursor + 10000;
    unsigned int* ebuf = (unsigned int*)(rowst + 10001);
    int*   eflag  = (int*)(ebuf + 170000);

    // zero zbuf/counts/cursor (contiguous) and the output accumulator
    hipMemsetAsync(zbuf, 0, 40000 * sizeof(float), stream);
    hipMemsetAsync(y, 0, (size_t)NBATCH * sizeof(float), stream);
    detect_kernel<<<1, 1, 0, stream>>>(ei, eflag);

    // weight hi/lo splits
    split_kernel<<<256,  256, 0, stream>>>(enc_w2, w2h, w2l, 65536);
    split_kernel<<<512,  256, 0, stream>>>(gat_w,  gwh, gwl, 131072);
    split_kernel<<<512,  256, 0, stream>>>(skip_w, swh, swl, 131072);
    split_kernel<<<2048, 256, 0, stream>>>(dec_w1, d1h, d1l, 524288);

    // enc1 (fp32): h1 = x @ enc_w1^T + b1
    gemm_kernel<64, 64, 16, 4, 4><<<dim3(157, 4), 256, 0, stream>>>(
        x, enc_w1, enc_b1, h1, N_NODES, DIM_H, DIM_IN);
    // LN + ReLU -> h1ln hi/lo
    ln_relu_split_kernel<<<2500, 256, 0, stream>>>(h1, ln_g, ln_b, h1ln_hi, h1ln_lo);
    // enc2 (MFMA): h = h1ln @ enc_w2^T + b2 -> h hi/lo
    mgemm<1><<<dim3(79, 2), 256, 0, stream>>>(
        h1ln_hi, h1ln_lo, w2h, w2l, enc_b2, nullptr, nullptr,
        nullptr, h_hi, h_lo, nullptr, nullptr, nullptr, N_NODES, DIM_H, DIM_H);
    // gat lin (MFMA): xs = h @ gat_w^T (fp32 out)
    mgemm<0><<<dim3(79, 4), 256, 0, stream>>>(
        h_hi, h_lo, gwh, gwl, nullptr, nullptr, nullptr,
        xs, nullptr, nullptr, nullptr, nullptr, nullptr, N_NODES, DIM_GAT, DIM_H);
    // attention + CSR + aggregate
    attn_coef_kernel<<<2500, 256, 0, stream>>>(xs, att_src, att_dst, asrc, adst);
    edge_w_kernel<<<(E_TOT + 255) / 256, 256, 0, stream>>>(
        ei, eflag, asrc, adst, wbuf, zbuf, counts);
    scan_kernel<<<1, 1024, 0, stream>>>(counts, rowst);
    scatter_kernel<<<(E_TOT + 255) / 256, 256, 0, stream>>>(
        ei, eflag, rowst, cursor, ebuf);
    agg_kernel<<<NBATCH, 256, 0, stream>>>(xs, wbuf, zbuf, rowst, ebuf, agg);
    // skip (MFMA): outb = elu(agg + gat_bias + h @ skip_w^T + skip_b) -> hi/lo
    mgemm<2><<<dim3(64, 4), 256, 0, stream>>>(
        h_hi, h_lo, swh, swl, skip_b, gat_bias, agg,
        nullptr, outb_hi, outb_lo, nullptr, nullptr, nullptr, NBATCH, DIM_GAT, DIM_H);
    // dec1 (MFMA) + fused dec2: y += leaky(outb @ dec_w1^T + b1) @ dec_w2^T + b2
    mgemm<3><<<dim3(64, 8), 256, 0, stream>>>(
        outb_hi, outb_lo, d1h, d1l, dec_b1, nullptr, nullptr,
        nullptr, nullptr, nullptr, dec_w2, dec_b2, y, NBATCH, DIM_DEC, DIM_GAT);
}

// Round 13
// 275.714 us; speedup vs baseline: 1.6457x; 1.0762x over previous
//
#include <hip/hip_runtime.h>

// ---------------------------------------------------------------------------
// GATEncoder fused pipeline. R12 = R10/R11 resubmit (broker timeouts):
//  - agg gather from bf16 xs (half bytes), ushort2/thread, 4-edge unroll.
//  - attn coefficients fused into gat mgemm epilogue (fp32 acc, shuffle
//    reduce + atomicAdd) — attn_coef_kernel and fp32 xs eliminated.
//  - everything else unchanged from R9 (validated: 296.7 µs, absmax 3.9e-3).
// ---------------------------------------------------------------------------

#define N_NODES  10000
#define N_EDGES  160000
#define E_TOT    (N_EDGES + N_NODES)
#define NBATCH   8192
#define DIM_IN   128
#define DIM_H    256
#define DIM_GAT  512
#define DIM_DEC  1024
#define MPAD     10112                 // 79 * 128

typedef short bf16x8 __attribute__((ext_vector_type(8)));   // 8 bf16 in 4 VGPRs
typedef float f32x4  __attribute__((ext_vector_type(4)));

__device__ __forceinline__ ushort f2bf(float f) {
    union { float f; unsigned u; } c; c.f = f;
    unsigned u = c.u + 0x7FFFu + ((c.u >> 16) & 1u);   // RNE
    return (ushort)(u >> 16);
}
__device__ __forceinline__ float bf2f(ushort h) {
    union { unsigned u; float f; } c; c.u = ((unsigned)h) << 16; return c.f;
}

// ---------------------------------------------------------------------------
// fp32 register-tiled GEMM (enc1 only: [10000,128] @ [128->256]).
// ---------------------------------------------------------------------------
template<int BM, int BN, int BK, int TM, int TN>
__global__ __launch_bounds__(256)
void gemm_kernel(const float* __restrict__ A, const float* __restrict__ W,
                 const float* __restrict__ bias, float* __restrict__ C,
                 int M, int N, int K)
{
    constexpr int TX = BN / TN;
    constexpr int TY = BM / TM;
    static_assert(TX * TY == 256, "block must be 256 threads");
    __shared__ float As[BK][BM + 4];
    __shared__ float Ws[BK][BN + 4];

    const int tid = threadIdx.x;
    const int tx  = tid % TX;
    const int ty  = tid / TX;
    const int bm  = blockIdx.x * BM;
    const int bn  = blockIdx.y * BN;

    float acc[TM][TN];
    #pragma unroll
    for (int i = 0; i < TM; ++i)
        #pragma unroll
        for (int j = 0; j < TN; ++j) acc[i][j] = 0.f;

    constexpr int A_LOADS = BM * BK / 4 / 256;
    constexpr int W_LOADS = BN * BK / 4 / 256;
    constexpr int KQ = BK / 4;

    for (int k0 = 0; k0 < K; k0 += BK) {
        #pragma unroll
        for (int l = 0; l < A_LOADS; ++l) {
            int idx = tid + l * 256, row = idx / KQ, kq = idx % KQ;
            int grow = bm + row;
            float4 v = make_float4(0.f, 0.f, 0.f, 0.f);
            if (grow < M)
                v = *reinterpret_cast<const float4*>(&A[(size_t)grow * K + k0 + kq * 4]);
            As[kq * 4 + 0][row] = v.x; As[kq * 4 + 1][row] = v.y;
            As[kq * 4 + 2][row] = v.z; As[kq * 4 + 3][row] = v.w;
        }
        #pragma unroll
        for (int l = 0; l < W_LOADS; ++l) {
            int idx = tid + l * 256, row = idx / KQ, kq = idx % KQ;
            float4 v = *reinterpret_cast<const float4*>(&W[(size_t)(bn + row) * K + k0 + kq * 4]);
            Ws[kq * 4 + 0][row] = v.x; Ws[kq * 4 + 1][row] = v.y;
            Ws[kq * 4 + 2][row] = v.z; Ws[kq * 4 + 3][row] = v.w;
        }
        __syncthreads();
        #pragma unroll
        for (int kk = 0; kk < BK; ++kk) {
            float af[TM], wf[TN];
            #pragma unroll
            for (int i = 0; i < TM; ++i) af[i] = As[kk][ty * TM + i];
            #pragma unroll
            for (int j = 0; j < TN; ++j) wf[j] = Ws[kk][tx * TN + j];
            #pragma unroll
            for (int i = 0; i < TM; ++i)
                #pragma unroll
                for (int j = 0; j < TN; ++j)
                    acc[i][j] = fmaf(af[i], wf[j], acc[i][j]);
        }
        __syncthreads();
    }

    #pragma unroll
    for (int i = 0; i < TM; ++i) {
        int grow = bm + ty * TM + i;
        if (grow < M) {
            #pragma unroll
            for (int j = 0; j < TN; ++j) {
                int gcol = bn + tx * TN + j;
                C[(size_t)grow * N + gcol] = acc[i][j] + bias[gcol];
            }
        }
    }
}

// ---------------------------------------------------------------------------
// Split-bf16 MFMA GEMM: C[M,N] = A[M,K] @ W[N,K]^T, 3-pass hi/lo.
// 128x128x64 tile, 4 waves (2x2), each wave 64x64 (4x4 16x16x32 frags).
// LDS tiles [128 rows][64 bf16], 16B-chunk XOR swizzle byte^=((row&7)<<4):
// inverse-swizzled global SOURCE + linear global_load_lds dest + swizzled
// ds_read (both-sides rule).
// EPI: 0 = bf16 xs out + fused attn-coef partials (gat);
//      1 = +bias, split hi/lo out (enc2);
//      2 = +bias+bias2+addmat, ELU(0.1), split hi/lo out (skip);
//      3 = +bias, leaky(0.1), fused dot-with-w2 -> atomicAdd y (dec1+dec2).
// ---------------------------------------------------------------------------
__device__ __forceinline__ void stage_tile(ushort* T, const ushort* __restrict__ G,
                                           int rowbase, int K, int k0, int tid, int wv)
{
    #pragma unroll
    for (int i = 0; i < 4; ++i) {
        int m   = i * 32 + (tid >> 3);                       // tile row
        int scb = ((tid & 7) << 4) ^ ((m & 7) << 4);         // src col byte (inv swz)
        const char* gsrc = (const char*)G + ((size_t)(rowbase + m) * K + k0) * 2 + scb;
        char* ldst = (char*)T + i * 4096 + wv * 1024;        // wave-uniform base
        __builtin_amdgcn_global_load_lds(
            (const __attribute__((address_space(1))) void*)gsrc,
            (__attribute__((address_space(3))) void*)ldst, 16, 0, 0);
    }
}

__device__ __forceinline__ bf16x8 ldfrag(const ushort* T, int row, int kcb)
{
    int addr = (row << 7) + (kcb ^ ((row & 7) << 4));        // swizzled read
    return *reinterpret_cast<const bf16x8*>(reinterpret_cast<const char*>(T) + addr);
}

template<int EPI>
__global__ __launch_bounds__(256, 2)
void mgemm(const ushort* __restrict__ Ah, const ushort* __restrict__ Al,
           const ushort* __restrict__ Wh, const ushort* __restrict__ Wl,
           const float* __restrict__ bias, const float* __restrict__ bias2,
           const float* __restrict__ addmat, float* __restrict__ outF,
           ushort* __restrict__ outHi, ushort* __restrict__ outLo,
           const float* __restrict__ w2, const float* __restrict__ b2,
           float* __restrict__ aS, float* __restrict__ aD,
           float* __restrict__ yout, int M, int N, int K)
{
    __shared__ __align__(16) ushort tAh[8192];
    __shared__ __align__(16) ushort tAl[8192];
    __shared__ __align__(16) ushort tWh[8192];
    __shared__ __align__(16) ushort tWl[8192];

    const int tid    = threadIdx.x;
    const int lane   = tid & 63;
    const int wv     = tid >> 6;
    const int wr     = wv >> 1, wc = wv & 1;
    const int bm     = blockIdx.x * 128;
    const int bn     = blockIdx.y * 128;
    const int lane15 = lane & 15;
    const int kgrp16 = (lane >> 4) << 4;      // byte offset of lane's k-slice
    const int r0     = (lane >> 4) << 2;      // C/D row group

    f32x4 acc[4][4];
    const f32x4 zero = {0.f, 0.f, 0.f, 0.f};
    #pragma unroll
    for (int i = 0; i < 4; ++i)
        #pragma unroll
        for (int j = 0; j < 4; ++j) acc[i][j] = zero;

    for (int k0 = 0; k0 < K; k0 += 64) {
        stage_tile(tAh, Ah, bm, K, k0, tid, wv);
        stage_tile(tAl, Al, bm, K, k0, tid, wv);
        stage_tile(tWh, Wh, bn, K, k0, tid, wv);
        stage_tile(tWl, Wl, bn, K, k0, tid, wv);
        __syncthreads();                       // drains vmcnt before barrier
        #pragma unroll
        for (int kk = 0; kk < 2; ++kk) {
            const int kcb = kk * 64 + kgrp16;
            bf16x8 ah[4], al[4], wh[4], wl[4];
            #pragma unroll
            for (int f = 0; f < 4; ++f) {
                ah[f] = ldfrag(tAh, wr * 64 + f * 16 + lane15, kcb);
                al[f] = ldfrag(tAl, wr * 64 + f * 16 + lane15, kcb);
                wh[f] = ldfrag(tWh, wc * 64 + f * 16 + lane15, kcb);
                wl[f] = ldfrag(tWl, wc * 64 + f * 16 + lane15, kcb);
            }
            #pragma unroll
            for (int fm = 0; fm < 4; ++fm)
                #pragma unroll
                for (int fn = 0; fn < 4; ++fn) {
                    acc[fm][fn] = __builtin_amdgcn_mfma_f32_16x16x32_bf16(ah[fm], wh[fn], acc[fm][fn], 0, 0, 0);
                    acc[fm][fn] = __builtin_amdgcn_mfma_f32_16x16x32_bf16(ah[fm], wl[fn], acc[fm][fn], 0, 0, 0);
                    acc[fm][fn] = __builtin_amdgcn_mfma_f32_16x16x32_bf16(al[fm], wh[fn], acc[fm][fn], 0, 0, 0);
                }
        }
        __syncthreads();
    }

    if (EPI == 0) {
        // gat: write bf16 xs + fused attention partial dots.
        // bias = att_src[512], bias2 = att_dst[512]; head uniform per block.
        const int head = bn >> 8;
        #pragma unroll
        for (int fm = 0; fm < 4; ++fm) {
            #pragma unroll
            for (int r = 0; r < 4; ++r) {
                int row = bm + wr * 64 + fm * 16 + r0 + r;
                if (row < M) {          // row uniform within 16-lane group
                    float sp = 0.f, dp = 0.f;
                    #pragma unroll
                    for (int fn = 0; fn < 4; ++fn) {
                        int col = bn + wc * 64 + fn * 16 + lane15;
                        float v = acc[fm][fn][r];
                        outHi[(size_t)row * N + col] = f2bf(v);
                        sp = fmaf(v, bias[col], sp);
                        dp = fmaf(v, bias2[col], dp);
                    }
                    sp += __shfl_xor(sp, 1); sp += __shfl_xor(sp, 2);
                    sp += __shfl_xor(sp, 4); sp += __shfl_xor(sp, 8);
                    dp += __shfl_xor(dp, 1); dp += __shfl_xor(dp, 2);
                    dp += __shfl_xor(dp, 4); dp += __shfl_xor(dp, 8);
                    if (lane15 == 0) {
                        atomicAdd(&aS[row * 2 + head], sp);
                        atomicAdd(&aD[row * 2 + head], dp);
                    }
                }
            }
        }
    } else if (EPI == 1 || EPI == 2) {
        #pragma unroll
        for (int fm = 0; fm < 4; ++fm) {
            #pragma unroll
            for (int r = 0; r < 4; ++r) {
                int row = bm + wr * 64 + fm * 16 + r0 + r;
                if (row < M) {
                    #pragma unroll
                    for (int fn = 0; fn < 4; ++fn) {
                        int col = bn + wc * 64 + fn * 16 + lane15;
                        float v = acc[fm][fn][r] + bias[col];
                        if (EPI == 2) {
                            v += bias2[col] + addmat[(size_t)row * N + col];
                            v = v > 0.f ? v : 0.1f * (expf(v) - 1.f);
                        }
                        ushort h = f2bf(v);
                        outHi[(size_t)row * N + col] = h;
                        outLo[(size_t)row * N + col] = f2bf(v - bf2f(h));
                    }
                }
            }
        }
    } else {
        // dec1 + fused dec2: y[row] += sum_col leaky(acc+b1)[col] * w2[col]
        #pragma unroll
        for (int fm = 0; fm < 4; ++fm) {
            #pragma unroll
            for (int r = 0; r < 4; ++r) {
                int row = bm + wr * 64 + fm * 16 + r0 + r;
                float part = 0.f;
                #pragma unroll
                for (int fn = 0; fn < 4; ++fn) {
                    int col = bn + wc * 64 + fn * 16 + lane15;
                    float v = acc[fm][fn][r] + bias[col];
                    v = v > 0.f ? v : 0.1f * v;
                    part = fmaf(v, w2[col], part);
                }
                part += __shfl_xor(part, 1);
                part += __shfl_xor(part, 2);
                part += __shfl_xor(part, 4);
                part += __shfl_xor(part, 8);
                if (lane15 == 0 && row < M) {
                    // b2 exactly once per row: only the wc==0 wave of y-block 0
                    float add = part + ((blockIdx.y == 0 && wc == 0) ? b2[0] : 0.f);
                    atomicAdd(&yout[row], add);
                }
            }
        }
    }
}

// ---------------------------------------------------------------------------
// Weight hi/lo split (elementwise).
// ---------------------------------------------------------------------------
__global__ __launch_bounds__(256)
void split_kernel(const float* __restrict__ src, ushort* __restrict__ hi,
                  ushort* __restrict__ lo, int n)
{
    int i = blockIdx.x * 256 + threadIdx.x;
    if (i < n) {
        float v = src[i];
        ushort h = f2bf(v);
        hi[i] = h;
        lo[i] = f2bf(v - bf2f(h));
    }
}

// ---------------------------------------------------------------------------
// edge_index dtype detection (int64 vs int32), device-side.
// ---------------------------------------------------------------------------
__global__ void detect_kernel(const int* __restrict__ ei32, int* __restrict__ eflag)
{
    if (blockIdx.x == 0 && threadIdx.x == 0) {
        int s = 0;
        #pragma unroll
        for (int i = 0; i < 64; ++i) s |= ei32[2 * i + 1];
        eflag[0] = (s == 0) ? 2 : 1;
    }
}

// ---------------------------------------------------------------------------
// LayerNorm(256) + ReLU -> hi/lo bf16 pair. One wave per row.
// ---------------------------------------------------------------------------
__global__ __launch_bounds__(256)
void ln_relu_split_kernel(const float* __restrict__ h1, const float* __restrict__ g,
                          const float* __restrict__ b, ushort* __restrict__ hi,
                          ushort* __restrict__ lo)
{
    int wave = threadIdx.x >> 6, lane = threadIdx.x & 63;
    int row = blockIdx.x * 4 + wave;
    if (row >= N_NODES) return;
    float4 v = *reinterpret_cast<const float4*>(&h1[(size_t)row * DIM_H + lane * 4]);
    float s  = v.x + v.y + v.z + v.w;
    float sq = v.x * v.x + v.y * v.y + v.z * v.z + v.w * v.w;
    #pragma unroll
    for (int m = 1; m <= 32; m <<= 1) { s += __shfl_xor(s, m); sq += __shfl_xor(sq, m); }
    float mu  = s * (1.0f / 256.0f);
    float var = sq * (1.0f / 256.0f) - mu * mu;
    float rs  = 1.0f / sqrtf(var + 1e-5f);
    float4 gg = *reinterpret_cast<const float4*>(&g[lane * 4]);
    float4 bb = *reinterpret_cast<const float4*>(&b[lane * 4]);
    float o[4];
    o[0] = fmaxf((v.x - mu) * rs * gg.x + bb.x, 0.f);
    o[1] = fmaxf((v.y - mu) * rs * gg.y + bb.y, 0.f);
    o[2] = fmaxf((v.z - mu) * rs * gg.z + bb.z, 0.f);
    o[3] = fmaxf((v.w - mu) * rs * gg.w + bb.w, 0.f);
    ushort4 vh, vl;
    ushort* ph = &vh.x; ushort* pl = &vl.x;
    #pragma unroll
    for (int q = 0; q < 4; ++q) {
        ushort hh = f2bf(o[q]);
        ph[q] = hh;
        pl[q] = f2bf(o[q] - bf2f(hh));
    }
    *reinterpret_cast<ushort4*>(&hi[(size_t)row * DIM_H + lane * 4]) = vh;
    *reinterpret_cast<ushort4*>(&lo[(size_t)row * DIM_H + lane * 4]) = vl;
}

// ---------------------------------------------------------------------------
// Edge pass: w = exp(leaky(a_src[src]+a_dst[tgt],0.2)); z[tgt]+=w; counts++.
// Max-subtraction skipped: alpha = w/z is identical; |e| bounded ~2 here.
// ---------------------------------------------------------------------------
__global__ __launch_bounds__(256)
void edge_w_kernel(const int* __restrict__ ei, const int* __restrict__ eflag,
                   const float* __restrict__ asrc, const float* __restrict__ adst,
                   float* __restrict__ wbuf, float* __restrict__ zbuf,
                   int* __restrict__ counts)
{
    int e = blockIdx.x * 256 + threadIdx.x;
    if (e >= E_TOT) return;
    const int stride = eflag[0];
    int src, tgt;
    if (e < N_EDGES) {
        src = ei[(size_t)stride * e];
        tgt = ei[(size_t)stride * (N_EDGES + e)];
    } else {
        src = tgt = e - N_EDGES;
    }
    #pragma unroll
    for (int hh = 0; hh < 2; ++hh) {
        float v = asrc[src * 2 + hh] + adst[tgt * 2 + hh];
        v = v > 0.f ? v : 0.2f * v;
        float w = expf(v);
        wbuf[e * 2 + hh] = w;
        atomicAdd(&zbuf[tgt * 2 + hh], w);
    }
    atomicAdd(&counts[tgt], 1);
}

// ---------------------------------------------------------------------------
// Exclusive prefix sum counts -> rowst. One block.
// ---------------------------------------------------------------------------
__global__ __launch_bounds__(1024)
void scan_kernel(const int* __restrict__ counts, int* __restrict__ rowst)
{
    __shared__ int part[1024];
    const int t = threadIdx.x;
    const int base = t * 10;
    int loc[10];
    int s = 0;
    #pragma unroll
    for (int i = 0; i < 10; ++i) {
        int idx = base + i;
        int v = (idx < N_NODES) ? counts[idx] : 0;
        loc[i] = s;
        s += v;
    }
    part[t] = s;
    __syncthreads();
    for (int off = 1; off < 1024; off <<= 1) {
        int v = (t >= off) ? part[t - off] : 0;
        __syncthreads();
        part[t] += v;
        __syncthreads();
    }
    int chunk_excl = part[t] - s;
    #pragma unroll
    for (int i = 0; i < 10; ++i) {
        int idx = base + i;
        if (idx <= N_NODES) rowst[idx] = chunk_excl + loc[i];
    }
}

// ---------------------------------------------------------------------------
// Scatter packed (e<<14)|src (unsigned!) into CSR buckets by target.
// ---------------------------------------------------------------------------
__global__ __launch_bounds__(256)
void scatter_kernel(const int* __restrict__ ei, const int* __restrict__ eflag,
                    const int* __restrict__ rowst,
                    int* __restrict__ cursor, unsigned int* __restrict__ ebuf)
{
    int e = blockIdx.x * 256 + threadIdx.x;
    if (e >= E_TOT) return;
    const int stride = eflag[0];
    int src, tgt;
    if (e < N_EDGES) {
        src = ei[(size_t)stride * e];
        tgt = ei[(size_t)stride * (N_EDGES + e)];
    } else {
        src = tgt = e - N_EDGES;
    }
    int pos = atomicAdd(&cursor[tgt], 1);
    ebuf[rowst[tgt] + pos] = ((unsigned int)e << 14) | (unsigned int)src;
}

// ---------------------------------------------------------------------------
// Gather-aggregate from bf16 xs: agg[n,:] = sum_e alpha_e * xs[src_e,:].
// Thread t owns cols 2t, 2t+1 (one ushort2 load/edge); head = t>>7.
// 4-edge manual unroll for memory-level parallelism.
// ---------------------------------------------------------------------------
__global__ __launch_bounds__(256)
void agg_kernel(const ushort* __restrict__ xs_b,
                const float* __restrict__ wbuf, const float* __restrict__ zbuf,
                const int* __restrict__ rowst, const unsigned int* __restrict__ ebuf,
                float* __restrict__ agg)
{
    const int n = blockIdx.x;
    const int t = threadIdx.x;
    const int h = t >> 7;                     // head for cols 2t, 2t+1
    const float inv = 1.0f / zbuf[n * 2 + h];
    float acc0 = 0.f, acc1 = 0.f;
    const int beg = rowst[n], end = rowst[n + 1];
    int j = beg;
    for (; j + 3 < end; j += 4) {
        unsigned pk0 = ebuf[j],     pk1 = ebuf[j + 1];
        unsigned pk2 = ebuf[j + 2], pk3 = ebuf[j + 3];
        float w0 = wbuf[(pk0 >> 14) * 2 + h];
        float w1 = wbuf[(pk1 >> 14) * 2 + h];
        float w2 = wbuf[(pk2 >> 14) * 2 + h];
        float w3 = wbuf[(pk3 >> 14) * 2 + h];
        ushort2 x0 = *reinterpret_cast<const ushort2*>(&xs_b[(size_t)(pk0 & 0x3FFFu) * DIM_GAT + 2 * t]);
        ushort2 x1 = *reinterpret_cast<const ushort2*>(&xs_b[(size_t)(pk1 & 0x3FFFu) * DIM_GAT + 2 * t]);
        ushort2 x2 = *reinterpret_cast<const ushort2*>(&xs_b[(size_t)(pk2 & 0x3FFFu) * DIM_GAT + 2 * t]);
        ushort2 x3 = *reinterpret_cast<const ushort2*>(&xs_b[(size_t)(pk3 & 0x3FFFu) * DIM_GAT + 2 * t]);
        float a0 = w0 * inv, a1 = w1 * inv, a2 = w2 * inv, a3 = w3 * inv;
        acc0 = fmaf(bf2f(x0.x), a0, acc0); acc1 = fmaf(bf2f(x0.y), a0, acc1);
        acc0 = fmaf(bf2f(x1.x), a1, acc0); acc1 = fmaf(bf2f(x1.y), a1, acc1);
        acc0 = fmaf(bf2f(x2.x), a2, acc0); acc1 = fmaf(bf2f(x2.y), a2, acc1);
        acc0 = fmaf(bf2f(x3.x), a3, acc0); acc1 = fmaf(bf2f(x3.y), a3, acc1);
    }
    for (; j < end; ++j) {
        unsigned pk = ebuf[j];
        float w = wbuf[(pk >> 14) * 2 + h];
        ushort2 x = *reinterpret_cast<const ushort2*>(&xs_b[(size_t)(pk & 0x3FFFu) * DIM_GAT + 2 * t]);
        float a = w * inv;
        acc0 = fmaf(bf2f(x.x), a, acc0);
        acc1 = fmaf(bf2f(x.y), a, acc1);
    }
    agg[(size_t)n * DIM_GAT + 2 * t]     = acc0;
    agg[(size_t)n * DIM_GAT + 2 * t + 1] = acc1;
}

// ---------------------------------------------------------------------------
extern "C" void kernel_launch(void* const* d_in, const int* in_sizes, int n_in,
                              void* d_out, int out_size, void* d_ws, size_t ws_size,
                              hipStream_t stream)
{
    const float* x        = (const float*)d_in[0];
    const int*   ei       = (const int*)  d_in[1];
    const float* enc_w1   = (const float*)d_in[3];
    const float* enc_b1   = (const float*)d_in[4];
    const float* ln_g     = (const float*)d_in[5];
    const float* ln_b     = (const float*)d_in[6];
    const float* enc_w2   = (const float*)d_in[7];
    const float* enc_b2   = (const float*)d_in[8];
    const float* gat_w    = (const float*)d_in[9];
    const float* att_src  = (const float*)d_in[10];
    const float* att_dst  = (const float*)d_in[11];
    const float* gat_bias = (const float*)d_in[12];
    const float* skip_w   = (const float*)d_in[13];
    const float* skip_b   = (const float*)d_in[14];
    const float* dec_w1   = (const float*)d_in[15];
    const float* dec_b1   = (const float*)d_in[16];
    const float* dec_w2   = (const float*)d_in[17];
    const float* dec_b2   = (const float*)d_in[18];
    float* y = (float*)d_out;

    // -------- workspace layout (floats); overlays are phase-disjoint -------
    float* ws = (float*)d_ws;
    // R0 overlay [0, 5242880):
    //   enc phase: h1 fp32 [10000*256] | h1ln_hi/lo ushort [10112*256]
    //   gat phase: xs_b ushort [10112*512] (overwrites h1 — dead by then)
    //   skip phase: outb_hi/lo ushort [8192*512] (overwrites xs_b — dead)
    float*  h1      = ws;
    ushort* h1ln_hi = (ushort*)(ws + 2560000);
    ushort* h1ln_lo = h1ln_hi + (size_t)MPAD * DIM_H;
    ushort* xs_b    = (ushort*)ws;
    ushort* outb_hi = (ushort*)ws;
    ushort* outb_lo = outb_hi + (size_t)NBATCH * DIM_GAT;
    // B: h hi/lo (live enc2 -> skip)
    ushort* h_hi = (ushort*)(ws + 5242880);
    ushort* h_lo = h_hi + (size_t)MPAD * DIM_H;
    // D: agg fp32
    float* agg = ws + 7842880;
    // F: split weights (ushort)
    ushort* wsp = (ushort*)(ws + 12037184);
    ushort* w2h = wsp;
    ushort* w2l = w2h + 65536;
    ushort* gwh = w2l + 65536;
    ushort* gwl = gwh + 131072;
    ushort* swh = gwl + 131072;
    ushort* swl = swh + 131072;
    ushort* d1h = swl + 131072;
    ushort* d1l = d1h + 524288;
    // S: edge/attention scratch. asrc..cursor contiguous for a single memset.
    float* S      = ws + 12889152;
    float* asrc   = S;                        // [10000,2]
    float* adst   = S + 20000;                // [10000,2]
    float* zbuf   = S + 40000;                // [10000,2]
    int*   counts = (int*)(S + 60000);        // [10000]
    int*   cursor = counts + 10000;           // [10000]
    float* wbuf   = S + 80000;                // [170000,2]
    int*   rowst  = (int*)(S + 420000);       // [10001]
    unsigned int* ebuf = (unsigned int*)(rowst + 10001); // [170000]
    int*   eflag  = (int*)(ebuf + 170000);    // [1]

    // zero asrc/adst/zbuf/counts/cursor (contiguous 80000 words) + y
    hipMemsetAsync(asrc, 0, 80000 * sizeof(float), stream);
    hipMemsetAsync(y, 0, (size_t)NBATCH * sizeof(float), stream);
    detect_kernel<<<1, 1, 0, stream>>>(ei, eflag);

    // weight hi/lo splits
    split_kernel<<<256,  256, 0, stream>>>(enc_w2, w2h, w2l, 65536);
    split_kernel<<<512,  256, 0, stream>>>(gat_w,  gwh, gwl, 131072);
    split_kernel<<<512,  256, 0, stream>>>(skip_w, swh, swl, 131072);
    split_kernel<<<2048, 256, 0, stream>>>(dec_w1, d1h, d1l, 524288);

    // enc1 (fp32): h1 = x @ enc_w1^T + b1
    gemm_kernel<64, 64, 16, 4, 4><<<dim3(157, 4), 256, 0, stream>>>(
        x, enc_w1, enc_b1, h1, N_NODES, DIM_H, DIM_IN);
    // LN + ReLU -> h1ln hi/lo
    ln_relu_split_kernel<<<2500, 256, 0, stream>>>(h1, ln_g, ln_b, h1ln_hi, h1ln_lo);
    // enc2 (MFMA): h = h1ln @ enc_w2^T + b2 -> h hi/lo
    mgemm<1><<<dim3(79, 2), 256, 0, stream>>>(
        h1ln_hi, h1ln_lo, w2h, w2l, enc_b2, nullptr, nullptr,
        nullptr, h_hi, h_lo, nullptr, nullptr, nullptr, nullptr, nullptr,
        N_NODES, DIM_H, DIM_H);
    // gat lin (MFMA): xs_b = bf16(h @ gat_w^T), attn coefs fused -> asrc/adst
    mgemm<0><<<dim3(79, 4), 256, 0, stream>>>(
        h_hi, h_lo, gwh, gwl, att_src, att_dst, nullptr,
        nullptr, xs_b, nullptr, nullptr, nullptr, asrc, adst, nullptr,
        N_NODES, DIM_GAT, DIM_H);
    // edge weights + CSR + aggregate
    edge_w_kernel<<<(E_TOT + 255) / 256, 256, 0, stream>>>(
        ei, eflag, asrc, adst, wbuf, zbuf, counts);
    scan_kernel<<<1, 1024, 0, stream>>>(counts, rowst);
    scatter_kernel<<<(E_TOT + 255) / 256, 256, 0, stream>>>(
        ei, eflag, rowst, cursor, ebuf);
    agg_kernel<<<NBATCH, 256, 0, stream>>>(xs_b, wbuf, zbuf, rowst, ebuf, agg);
    // skip (MFMA): outb = elu(agg + gat_bias + h @ skip_w^T + skip_b) -> hi/lo
    mgemm<2><<<dim3(64, 4), 256, 0, stream>>>(
        h_hi, h_lo, swh, swl, skip_b, gat_bias, agg,
        nullptr, outb_hi, outb_lo, nullptr, nullptr, nullptr, nullptr, nullptr,
        NBATCH, DIM_GAT, DIM_H);
    // dec1 (MFMA) + fused dec2: y += leaky(outb @ dec_w1^T + b1) @ dec_w2^T + b2
    mgemm<3><<<dim3(64, 8), 256, 0, stream>>>(
        outb_hi, outb_lo, d1h, d1l, dec_b1, nullptr, nullptr,
        nullptr, nullptr, nullptr, dec_w2, dec_b2, nullptr, nullptr, y,
        NBATCH, DIM_DEC, DIM_GAT);
}